// Round 1
// baseline (140.404 us; speedup 1.0000x reference)
//
#include <hip/hip_runtime.h>

typedef unsigned short u16;
typedef unsigned int u32;
typedef __attribute__((ext_vector_type(8))) short short8;
typedef __attribute__((ext_vector_type(4))) float f32x4;
typedef __attribute__((ext_vector_type(4))) u16 u16x4;

#define NBATCH 2
#define NC 128
#define NN 147456          // 16*96*96
#define NCHUNK 1152        // NN / 128
#define G1_PARTS 256       // partial-Gram sets per batch
#define N3_PER_B 1152      // NN / 128 n-tiles per batch

__device__ __forceinline__ u16 bf16rne(float f) {
  u32 u = __builtin_bit_cast(u32, f);
  return (u16)((u + 0x7FFFu + ((u >> 16) & 1u)) >> 16);
}
__device__ __forceinline__ float bf2f(u16 h) {
  u32 u = ((u32)h) << 16;
  return __builtin_bit_cast(float, u);
}

// ---------------------------------------------------------------------------
// Stage 1: partial Gram  energy[b][c][d] = sum_k q[c,k] q[d,k]
// split bf16: q = hi + lo ; G ~= Hh*Hh^T + Hh*Lo^T + Lo*Hh^T  (3 MFMAs)
// Each block owns K-chunks ch = pi, pi+256, ... and writes ONE 128x128 fp32
// partial into d_out (used as scratch).
// ---------------------------------------------------------------------------
__global__ __launch_bounds__(256, 2)
void gram_k(const float* __restrict__ x, float* __restrict__ part) {
  __shared__ u16 hi[128 * 128];
  __shared__ u16 lo[128 * 128];
  const int tid = threadIdx.x;
  const int bid = blockIdx.x;
  const int b   = bid >> 8;        // 256 blocks per batch
  const int pi  = bid & 255;
  const int w   = tid >> 6;        // wave 0..3
  const int l   = tid & 63;
  const int grp = l >> 4;          // k-group 0..3
  const int lr  = l & 15;          // row-in-tile
  const int swz = lr << 3;         // LDS XOR swizzle (ushort units)
  const float* xb = x + (size_t)b * NC * NN;

  f32x4 acc[2][8];
#pragma unroll
  for (int i = 0; i < 2; ++i)
#pragma unroll
    for (int j = 0; j < 8; ++j) acc[i][j] = (f32x4){0.f, 0.f, 0.f, 0.f};

  const int lrow = tid >> 5;          // 0..7
  const int lcol = (tid & 31) << 2;   // 0..124 step 4

  for (int ch = pi; ch < NCHUNK; ch += G1_PARTS) {
    const int k0 = ch << 7;
    __syncthreads();  // protect LDS from previous iteration's readers
#pragma unroll
    for (int j = 0; j < 16; ++j) {
      const int row = (j << 3) + lrow;
      const float4 v = *(const float4*)(xb + (size_t)row * NN + (k0 + lcol));
      const u16 h0 = bf16rne(v.x), h1 = bf16rne(v.y), h2 = bf16rne(v.z), h3 = bf16rne(v.w);
      const u16 g0 = bf16rne(v.x - bf2f(h0)), g1 = bf16rne(v.y - bf2f(h1));
      const u16 g2 = bf16rne(v.z - bf2f(h2)), g3 = bf16rne(v.w - bf2f(h3));
      const int idx = (row << 7) + (lcol ^ ((row & 15) << 3));
      *(u16x4*)(hi + idx) = (u16x4){h0, h1, h2, h3};
      *(u16x4*)(lo + idx) = (u16x4){g0, g1, g2, g3};
    }
    __syncthreads();

    const int m0 = (w << 5) + lr;
    const int m1 = m0 + 16;
#pragma unroll
    for (int kk = 0; kk < 128; kk += 32) {
      const int kb = kk + (grp << 3);
      const short8 Ah0 = *(const short8*)(hi + (m0 << 7) + (kb ^ swz));
      const short8 Al0 = *(const short8*)(lo + (m0 << 7) + (kb ^ swz));
      const short8 Ah1 = *(const short8*)(hi + (m1 << 7) + (kb ^ swz));
      const short8 Al1 = *(const short8*)(lo + (m1 << 7) + (kb ^ swz));
#pragma unroll
      for (int nt = 0; nt < 8; ++nt) {
        const int nr  = (nt << 4) + lr;
        const int bix = (nr << 7) + (kb ^ swz);
        const short8 Bh = *(const short8*)(hi + bix);
        const short8 Bl = *(const short8*)(lo + bix);
        acc[0][nt] = __builtin_amdgcn_mfma_f32_16x16x32_bf16(Ah0, Bh, acc[0][nt], 0, 0, 0);
        acc[0][nt] = __builtin_amdgcn_mfma_f32_16x16x32_bf16(Ah0, Bl, acc[0][nt], 0, 0, 0);
        acc[0][nt] = __builtin_amdgcn_mfma_f32_16x16x32_bf16(Al0, Bh, acc[0][nt], 0, 0, 0);
        acc[1][nt] = __builtin_amdgcn_mfma_f32_16x16x32_bf16(Ah1, Bh, acc[1][nt], 0, 0, 0);
        acc[1][nt] = __builtin_amdgcn_mfma_f32_16x16x32_bf16(Ah1, Bl, acc[1][nt], 0, 0, 0);
        acc[1][nt] = __builtin_amdgcn_mfma_f32_16x16x32_bf16(Al1, Bh, acc[1][nt], 0, 0, 0);
      }
    }
  }

  float* pb = part + (size_t)bid * 16384;
#pragma unroll
  for (int mt = 0; mt < 2; ++mt)
#pragma unroll
    for (int nt = 0; nt < 8; ++nt)
#pragma unroll
      for (int r = 0; r < 4; ++r) {
        const int row = (w << 5) + (mt << 4) + (grp << 2) + r;  // C/D: row = 4*(l>>4)+r
        const int col = (nt << 4) + lr;                         // C/D: col = l&15
        pb[(row << 7) + col] = acc[mt][nt][r];
      }
}

// ---------------------------------------------------------------------------
// Stage 2: reduce partials + softmax(-energy) row-wise, emit bf16 attn to ws.
// softmax(e_max - e) == softmax(-e)  (shift invariance)
// ---------------------------------------------------------------------------
__global__ __launch_bounds__(128)
void soft_k(const float* __restrict__ part, u16* __restrict__ attn) {
  const int b = blockIdx.x >> 7;
  const int c = blockIdx.x & 127;
  const int d = threadIdx.x;
  __shared__ float red[128];
  float e = 0.f;
  const float* p0 = part + ((size_t)(b * G1_PARTS) << 14) + (c << 7) + d;
  for (int p = 0; p < G1_PARTS; ++p) e += p0[(size_t)p << 14];
  red[d] = e;
  __syncthreads();
#pragma unroll
  for (int s = 64; s > 0; s >>= 1) {
    if (d < s) red[d] = fminf(red[d], red[d + s]);
    __syncthreads();
  }
  const float emin = red[0];
  __syncthreads();
  const float pr = __expf(emin - e);  // arg <= 0, no overflow
  red[d] = pr;
  __syncthreads();
#pragma unroll
  for (int s = 64; s > 0; s >>= 1) {
    if (d < s) red[d] += red[d + s];
    __syncthreads();
  }
  const float inv = 1.f / red[0];
  attn[(((size_t)b) << 14) + (c << 7) + d] = bf16rne(pr * inv);
}

// ---------------------------------------------------------------------------
// Stage 3: out = x + gamma * attn @ q.  attn (bf16) in LDS as A operand;
// B fragments (k = d contiguous per lane) loaded directly from global fp32,
// split hi/lo in-register.  Residual x re-read in epilogue (L2-hit).
// ---------------------------------------------------------------------------
__global__ __launch_bounds__(256, 2)
void pv_k(const float* __restrict__ x, const u16* __restrict__ attn,
          const float* __restrict__ gamma, float* __restrict__ out) {
  __shared__ u16 at[128 * 128];
  const int tid = threadIdx.x;
  const int bid = blockIdx.x;
  const int b   = bid / N3_PER_B;
  const int nb  = (bid % N3_PER_B) << 7;
  const int w   = tid >> 6, l = tid & 63, grp = l >> 4, lr = l & 15;
  const int swz = lr << 3;
  const size_t bbase = (size_t)b * NC * NN;
  const u16* ab = attn + (((size_t)b) << 14);

#pragma unroll
  for (int j = 0; j < 8; ++j) {
    const int idx = (j << 8) + tid;
    const int c  = idx >> 4;
    const int d0 = (idx & 15) << 3;
    const int dst = (c << 7) + (d0 ^ ((c & 15) << 3));
    *(short8*)(at + dst) = *(const short8*)(ab + (c << 7) + d0);
  }
  __syncthreads();

  f32x4 acc[8][2];
#pragma unroll
  for (int i = 0; i < 8; ++i) {
    acc[i][0] = (f32x4){0.f, 0.f, 0.f, 0.f};
    acc[i][1] = (f32x4){0.f, 0.f, 0.f, 0.f};
  }

  const int n0 = nb + (w << 5) + lr;
#pragma unroll
  for (int kk = 0; kk < 128; kk += 32) {
    const int d0 = kk + (grp << 3);
    short8 Bh[2], Bl[2];
#pragma unroll
    for (int t = 0; t < 2; ++t) {
      const int n = n0 + (t << 4);
      const float* src = x + bbase + (size_t)d0 * NN + n;
      float f[8];
#pragma unroll
      for (int i = 0; i < 8; ++i) f[i] = src[(size_t)i * NN];
      u16 h[8], g[8];
#pragma unroll
      for (int i = 0; i < 8; ++i) {
        h[i] = bf16rne(f[i]);
        g[i] = bf16rne(f[i] - bf2f(h[i]));
      }
      Bh[t] = (short8){(short)h[0], (short)h[1], (short)h[2], (short)h[3],
                       (short)h[4], (short)h[5], (short)h[6], (short)h[7]};
      Bl[t] = (short8){(short)g[0], (short)g[1], (short)g[2], (short)g[3],
                       (short)g[4], (short)g[5], (short)g[6], (short)g[7]};
    }
#pragma unroll
    for (int mt = 0; mt < 8; ++mt) {
      const int mrow = (mt << 4) + lr;
      const short8 Ah = *(const short8*)(at + (mrow << 7) + ((kk + (grp << 3)) ^ swz));
#pragma unroll
      for (int t = 0; t < 2; ++t) {
        acc[mt][t] = __builtin_amdgcn_mfma_f32_16x16x32_bf16(Ah, Bh[t], acc[mt][t], 0, 0, 0);
        acc[mt][t] = __builtin_amdgcn_mfma_f32_16x16x32_bf16(Ah, Bl[t], acc[mt][t], 0, 0, 0);
      }
    }
  }

  const float gm = gamma[0];
#pragma unroll
  for (int mt = 0; mt < 8; ++mt)
#pragma unroll
    for (int t = 0; t < 2; ++t)
#pragma unroll
      for (int r = 0; r < 4; ++r) {
        const int c = (mt << 4) + (grp << 2) + r;
        const int n = n0 + (t << 4);
        const size_t off = bbase + (size_t)c * NN + n;
        out[off] = x[off] + gm * acc[mt][t][r];
      }
}

extern "C" void kernel_launch(void* const* d_in, const int* in_sizes, int n_in,
                              void* d_out, int out_size, void* d_ws, size_t ws_size,
                              hipStream_t stream) {
  (void)in_sizes; (void)n_in; (void)out_size; (void)ws_size;
  const float* x     = (const float*)d_in[0];
  const float* gamma = (const float*)d_in[1];
  float* out  = (float*)d_out;
  u16*   attn = (u16*)d_ws;          // 2*128*128 bf16 = 64 KiB
  float* part = out;                  // reuse d_out as partial-Gram scratch (33.5 MB)

  gram_k<<<dim3(2 * G1_PARTS), dim3(256), 0, stream>>>(x, part);
  soft_k<<<dim3(2 * 128),      dim3(128), 0, stream>>>(part, attn);
  pv_k  <<<dim3(2 * N3_PER_B), dim3(256), 0, stream>>>(x, attn, gamma, out);
}

// Round 2
// 118.476 us; speedup vs baseline: 1.1851x; 1.1851x over previous
//
#include <hip/hip_runtime.h>

typedef unsigned short u16;
typedef unsigned int u32;
typedef __attribute__((ext_vector_type(8))) short short8;
typedef __attribute__((ext_vector_type(4))) float f32x4;
typedef __attribute__((ext_vector_type(4))) u16 u16x4;

#define NBATCH 2
#define NC 128
#define NN 147456          // 16*96*96
#define CH 64              // k-depth per chunk (double-buffered)
#define NCH (NN / CH)      // 2304 chunks per batch
#define G1_PARTS 256       // blocks per batch -> 9 chunks per block
#define N3_PER_B 1152      // NN / 128 n-tiles per batch (stage 3)

__device__ __forceinline__ u16 bf16rne(float f) {
  u32 u = __builtin_bit_cast(u32, f);
  return (u16)((u + 0x7FFFu + ((u >> 16) & 1u)) >> 16);
}
__device__ __forceinline__ float bf2f(u16 h) {
  u32 u = ((u32)h) << 16;
  return __builtin_bit_cast(float, u);
}
// truncation split: h = top16(f), g = rne(f - h).  Dropped lo*lo term is
// ~sqrt(K)*2^-17 absolute on off-diag energies -> negligible vs softmax gaps.
__device__ __forceinline__ void split2(float f, u16& h, u16& g) {
  u32 u = __builtin_bit_cast(u32, f);
  h = (u16)(u >> 16);
  float hf = __builtin_bit_cast(float, u & 0xFFFF0000u);
  g = bf16rne(f - hf);
}

// ---------------------------------------------------------------------------
// Stage 1: partial Gram, BK=64 double-buffered software pipeline.
// Per iteration: issue loads(chunk i+1) -> MFMA(buf i) -> convert+write(buf i+1)
// -> barrier.  Loads stay in flight across the whole MFMA phase.
// ---------------------------------------------------------------------------
__global__ __launch_bounds__(256, 2)
void gram_k(const float* __restrict__ x, float* __restrict__ part) {
  __shared__ u16 hi[2][128 * CH];
  __shared__ u16 lo[2][128 * CH];
  const int tid = threadIdx.x;
  const int bid = blockIdx.x;
  const int b   = bid >> 8;
  const int pi  = bid & 255;
  const int w   = tid >> 6;        // wave 0..3
  const int l   = tid & 63;
  const int grp = l >> 4;          // k-group 0..3
  const int lr  = l & 15;          // row-in-tile
  const int swz = (lr & 7) << 3;   // XOR swizzle (u16 units), row&7 == lr&7
  const float* xb = x + (size_t)b * NC * NN;

  // staging geometry: 128 rows x 64 floats = 2048 float4, 8 per thread
  const int col4 = tid & 15;        // float4 index within row
  const int r0   = tid >> 4;        // row base 0..15, rows r0+16j

  f32x4 acc[2][8];
#pragma unroll
  for (int i = 0; i < 2; ++i)
#pragma unroll
    for (int j = 0; j < 8; ++j) acc[i][j] = (f32x4){0.f, 0.f, 0.f, 0.f};

  float4 v[8];

  auto issue = [&](int ch) {
    const int k0 = ch * CH + (col4 << 2);
#pragma unroll
    for (int j = 0; j < 8; ++j)
      v[j] = *(const float4*)(xb + (size_t)(r0 + (j << 4)) * NN + k0);
  };
  auto stage = [&](int bb) {
    u16* H = &hi[bb][0];
    u16* L = &lo[bb][0];
#pragma unroll
    for (int j = 0; j < 8; ++j) {
      const int row = r0 + (j << 4);
      const int idx = (row << 6) + ((col4 << 2) ^ ((row & 7) << 3));
      u16 h0, h1, h2, h3, g0, g1, g2, g3;
      split2(v[j].x, h0, g0); split2(v[j].y, h1, g1);
      split2(v[j].z, h2, g2); split2(v[j].w, h3, g3);
      *(u16x4*)(H + idx) = (u16x4){h0, h1, h2, h3};
      *(u16x4*)(L + idx) = (u16x4){g0, g1, g2, g3};
    }
  };
  const int m0 = (w << 5) + lr;
  const int m1 = m0 + 16;
  auto mma = [&](int bb) {
    const u16* H = &hi[bb][0];
    const u16* L = &lo[bb][0];
#pragma unroll
    for (int kk = 0; kk < CH; kk += 32) {
      const int kv = (kk + (grp << 3)) ^ swz;
      const short8 Ah0 = *(const short8*)(H + (m0 << 6) + kv);
      const short8 Al0 = *(const short8*)(L + (m0 << 6) + kv);
      const short8 Ah1 = *(const short8*)(H + (m1 << 6) + kv);
      const short8 Al1 = *(const short8*)(L + (m1 << 6) + kv);
#pragma unroll
      for (int nt = 0; nt < 8; ++nt) {
        const int nr  = (nt << 4) + lr;
        const int bix = (nr << 6) + kv;
        const short8 Bh = *(const short8*)(H + bix);
        const short8 Bl = *(const short8*)(L + bix);
        acc[0][nt] = __builtin_amdgcn_mfma_f32_16x16x32_bf16(Ah0, Bh, acc[0][nt], 0, 0, 0);
        acc[0][nt] = __builtin_amdgcn_mfma_f32_16x16x32_bf16(Ah0, Bl, acc[0][nt], 0, 0, 0);
        acc[0][nt] = __builtin_amdgcn_mfma_f32_16x16x32_bf16(Al0, Bh, acc[0][nt], 0, 0, 0);
        acc[1][nt] = __builtin_amdgcn_mfma_f32_16x16x32_bf16(Ah1, Bh, acc[1][nt], 0, 0, 0);
        acc[1][nt] = __builtin_amdgcn_mfma_f32_16x16x32_bf16(Ah1, Bl, acc[1][nt], 0, 0, 0);
        acc[1][nt] = __builtin_amdgcn_mfma_f32_16x16x32_bf16(Al1, Bh, acc[1][nt], 0, 0, 0);
      }
    }
  };

  // prologue: chunk 0
  issue(pi);
  stage(0);
  __syncthreads();

  const int NITER = NCH / G1_PARTS;  // 9
  for (int i = 0; i < NITER; ++i) {
    if (i + 1 < NITER) issue(pi + (i + 1) * G1_PARTS);  // in flight across MFMA
    mma(i & 1);
    if (i + 1 < NITER) stage((i + 1) & 1);              // vmcnt wait lands here
    __syncthreads();
  }

  float* pb = part + (size_t)bid * 16384;
#pragma unroll
  for (int mt = 0; mt < 2; ++mt)
#pragma unroll
    for (int nt = 0; nt < 8; ++nt)
#pragma unroll
      for (int r = 0; r < 4; ++r) {
        const int row = (w << 5) + (mt << 4) + (grp << 2) + r;  // C/D: row = 4*(l>>4)+r
        const int col = (nt << 4) + lr;                         // C/D: col = l&15
        pb[(row << 7) + col] = acc[mt][nt][r];
      }
}

// ---------------------------------------------------------------------------
// Stage 2: reduce partials + softmax(-energy) row-wise, emit bf16 attn to ws.
// ---------------------------------------------------------------------------
__global__ __launch_bounds__(128)
void soft_k(const float* __restrict__ part, u16* __restrict__ attn) {
  const int b = blockIdx.x >> 7;
  const int c = blockIdx.x & 127;
  const int d = threadIdx.x;
  __shared__ float red[128];
  float e = 0.f;
  const float* p0 = part + ((size_t)(b * G1_PARTS) << 14) + (c << 7) + d;
  for (int p = 0; p < G1_PARTS; ++p) e += p0[(size_t)p << 14];
  red[d] = e;
  __syncthreads();
#pragma unroll
  for (int s = 64; s > 0; s >>= 1) {
    if (d < s) red[d] = fminf(red[d], red[d + s]);
    __syncthreads();
  }
  const float emin = red[0];
  __syncthreads();
  const float pr = __expf(emin - e);  // arg <= 0, no overflow
  red[d] = pr;
  __syncthreads();
#pragma unroll
  for (int s = 64; s > 0; s >>= 1) {
    if (d < s) red[d] += red[d + s];
    __syncthreads();
  }
  const float inv = 1.f / red[0];
  attn[(((size_t)b) << 14) + (c << 7) + d] = bf16rne(pr * inv);
}

// ---------------------------------------------------------------------------
// Stage 3: out = x + gamma * attn @ q.  (unchanged from R1 — near L3 floor)
// ---------------------------------------------------------------------------
__global__ __launch_bounds__(256, 2)
void pv_k(const float* __restrict__ x, const u16* __restrict__ attn,
          const float* __restrict__ gamma, float* __restrict__ out) {
  __shared__ u16 at[128 * 128];
  const int tid = threadIdx.x;
  const int bid = blockIdx.x;
  const int b   = bid / N3_PER_B;
  const int nb  = (bid % N3_PER_B) << 7;
  const int w   = tid >> 6, l = tid & 63, grp = l >> 4, lr = l & 15;
  const int swz = lr << 3;
  const size_t bbase = (size_t)b * NC * NN;
  const u16* ab = attn + (((size_t)b) << 14);

#pragma unroll
  for (int j = 0; j < 8; ++j) {
    const int idx = (j << 8) + tid;
    const int c  = idx >> 4;
    const int d0 = (idx & 15) << 3;
    const int dst = (c << 7) + (d0 ^ ((c & 15) << 3));
    *(short8*)(at + dst) = *(const short8*)(ab + (c << 7) + d0);
  }
  __syncthreads();

  f32x4 acc[8][2];
#pragma unroll
  for (int i = 0; i < 8; ++i) {
    acc[i][0] = (f32x4){0.f, 0.f, 0.f, 0.f};
    acc[i][1] = (f32x4){0.f, 0.f, 0.f, 0.f};
  }

  const int n0 = nb + (w << 5) + lr;
#pragma unroll
  for (int kk = 0; kk < 128; kk += 32) {
    const int d0 = kk + (grp << 3);
    short8 Bh[2], Bl[2];
#pragma unroll
    for (int t = 0; t < 2; ++t) {
      const int n = n0 + (t << 4);
      const float* src = x + bbase + (size_t)d0 * NN + n;
      float f[8];
#pragma unroll
      for (int i = 0; i < 8; ++i) f[i] = src[(size_t)i * NN];
      u16 h[8], g[8];
#pragma unroll
      for (int i = 0; i < 8; ++i) {
        h[i] = bf16rne(f[i]);
        g[i] = bf16rne(f[i] - bf2f(h[i]));
      }
      Bh[t] = (short8){(short)h[0], (short)h[1], (short)h[2], (short)h[3],
                       (short)h[4], (short)h[5], (short)h[6], (short)h[7]};
      Bl[t] = (short8){(short)g[0], (short)g[1], (short)g[2], (short)g[3],
                       (short)g[4], (short)g[5], (short)g[6], (short)g[7]};
    }
#pragma unroll
    for (int mt = 0; mt < 8; ++mt) {
      const int mrow = (mt << 4) + lr;
      const short8 Ah = *(const short8*)(at + (mrow << 7) + ((kk + (grp << 3)) ^ swz));
#pragma unroll
      for (int t = 0; t < 2; ++t) {
        acc[mt][t] = __builtin_amdgcn_mfma_f32_16x16x32_bf16(Ah, Bh[t], acc[mt][t], 0, 0, 0);
        acc[mt][t] = __builtin_amdgcn_mfma_f32_16x16x32_bf16(Ah, Bl[t], acc[mt][t], 0, 0, 0);
      }
    }
  }

  const float gm = gamma[0];
#pragma unroll
  for (int mt = 0; mt < 8; ++mt)
#pragma unroll
    for (int t = 0; t < 2; ++t)
#pragma unroll
      for (int r = 0; r < 4; ++r) {
        const int c = (mt << 4) + (grp << 2) + r;
        const int n = n0 + (t << 4);
        const size_t off = bbase + (size_t)c * NN + n;
        out[off] = x[off] + gm * acc[mt][t][r];
      }
}

extern "C" void kernel_launch(void* const* d_in, const int* in_sizes, int n_in,
                              void* d_out, int out_size, void* d_ws, size_t ws_size,
                              hipStream_t stream) {
  (void)in_sizes; (void)n_in; (void)out_size; (void)ws_size;
  const float* x     = (const float*)d_in[0];
  const float* gamma = (const float*)d_in[1];
  float* out  = (float*)d_out;
  u16*   attn = (u16*)d_ws;          // 2*128*128 bf16 = 64 KiB
  float* part = out;                  // reuse d_out as partial-Gram scratch (33.5 MB)

  gram_k<<<dim3(2 * G1_PARTS), dim3(256), 0, stream>>>(x, part);
  soft_k<<<dim3(2 * 128),      dim3(128), 0, stream>>>(part, attn);
  pv_k  <<<dim3(2 * N3_PER_B), dim3(256), 0, stream>>>(x, attn, gamma, out);
}